// Round 1
// baseline (1590.431 us; speedup 1.0000x reference)
//
#include <hip/hip_runtime.h>
#include <cstdint>
#include <cstddef>

#define HDIM 2048
#define IDIM 5504
#define NEXP 8
#define NTOK 4096
#define NROWS (2 * NTOK)

typedef _Float16 half8 __attribute__((ext_vector_type(8)));
typedef _Float16 half4v __attribute__((ext_vector_type(4)));
typedef float floatx4 __attribute__((ext_vector_type(4)));

// ---------------- workspace layout (bytes) ----------------
#define XH_OFF   0                                   // fp16 x  [4096][2048]  16 MB
#define HB_OFF   (XH_OFF + (size_t)NTOK * HDIM * 2)  // fp16 h  [8192][5504]  90 MB
#define BTOK_OFF (HB_OFF + (size_t)NROWS * IDIM * 2) // int  [8192]
#define BW_OFF   (BTOK_OFF + 32768)                  // float[8192]
#define TOKP_OFF (BW_OFF + 32768)                    // int  [4096]
#define TOKW_OFF (TOKP_OFF + 16384)                  // float2[4096]
#define META_OFF (TOKW_OFF + 32768)                  // int[32]: cnt[8], off[9], cursor[8]

// ---------------- small kernels ----------------
__global__ void cvt_x_kernel(const float4* __restrict__ x, half4v* __restrict__ xh, int n4) {
  int i = blockIdx.x * blockDim.x + threadIdx.x;
  int st = gridDim.x * blockDim.x;
  for (; i < n4; i += st) {
    float4 v = x[i];
    half4v o = { (_Float16)v.x, (_Float16)v.y, (_Float16)v.z, (_Float16)v.w };
    xh[i] = o;
  }
}

__global__ void router_kernel(const float* __restrict__ x, const float* __restrict__ rw,
                              int* __restrict__ tokp, float2* __restrict__ tokw,
                              int* __restrict__ cnt) {
  int t = blockIdx.x * 4 + (threadIdx.x >> 6);
  int lane = threadIdx.x & 63;
  const float4* xr = (const float4*)(x + (size_t)t * HDIM);
  float acc[NEXP];
#pragma unroll
  for (int e = 0; e < NEXP; ++e) acc[e] = 0.f;
#pragma unroll
  for (int it = 0; it < HDIM / 256; ++it) {  // 8 iters of float4
    float4 xv = xr[lane + 64 * it];
#pragma unroll
    for (int e = 0; e < NEXP; ++e) {
      float4 wv = ((const float4*)(rw + (size_t)e * HDIM))[lane + 64 * it];
      acc[e] += xv.x * wv.x + xv.y * wv.y + xv.z * wv.z + xv.w * wv.w;
    }
  }
#pragma unroll
  for (int off = 32; off > 0; off >>= 1) {
#pragma unroll
    for (int e = 0; e < NEXP; ++e) acc[e] += __shfl_xor(acc[e], off);
  }
  if (lane == 0) {
    int e0 = 0; float v0 = acc[0];
#pragma unroll
    for (int e = 1; e < NEXP; ++e) {
      if (acc[e] > v0) { v0 = acc[e]; e0 = e; }   // strict > : lowest idx on tie (lax.top_k)
    }
    int e1 = -1; float v1 = -3.0e38f;
#pragma unroll
    for (int e = 0; e < NEXP; ++e) {
      if (e == e0) continue;
      if (acc[e] > v1) { v1 = acc[e]; e1 = e; }
    }
    float w0 = 1.f / (1.f + __expf(v1 - v0));     // softmax over top-2 (v0 >= v1, stable)
    tokp[t] = e0 | (e1 << 8);
    tokw[t] = make_float2(w0, 1.f - w0);
    atomicAdd(&cnt[e0], 1);
    atomicAdd(&cnt[e1], 1);
  }
}

__global__ void scan_kernel(const int* __restrict__ cnt, int* __restrict__ offp) {
  if (threadIdx.x == 0) {
    int s = 0;
    for (int e = 0; e < NEXP; ++e) { offp[e] = s; s += cnt[e]; }
    offp[NEXP] = s;
  }
}

__global__ void scatter_kernel(const int* __restrict__ tokp, const float2* __restrict__ tokw,
                               const int* __restrict__ offp, int* __restrict__ cursor,
                               int* __restrict__ btok, float* __restrict__ bw) {
  int t = blockIdx.x * blockDim.x + threadIdx.x;
  if (t >= NTOK) return;
  int p = tokp[t];
  float2 w = tokw[t];
  int e0 = p & 0xff, e1 = (p >> 8) & 0xff;
  int r0 = offp[e0] + atomicAdd(&cursor[e0], 1);
  btok[r0] = t; bw[r0] = w.x;
  int r1 = offp[e1] + atomicAdd(&cursor[e1], 1);
  btok[r1] = t; bw[r1] = w.y;
}

// ---------------- stage 1: h = silu(X Wg^T) * (X Wu^T)  (per expert, gathered rows) ----------------
// tile: 128 rows x 64 cols (dual matrices), BK=32, 4 waves (2M x 2N), 16x16x32 f16 MFMA
__global__ __launch_bounds__(256) void stage1_kernel(
    const _Float16* __restrict__ xh, const float* __restrict__ Wg, const float* __restrict__ Wu,
    const int* __restrict__ offp, const int* __restrict__ btok, _Float16* __restrict__ hb) {
  int e = blockIdx.z;
  int base = offp[e];
  int ne = offp[e + 1] - base;
  int rt = blockIdx.y;
  if (rt * 128 >= ne) return;
  int ct = blockIdx.x;                       // 0..85, col base ct*64
  int valid = ne - rt * 128; if (valid > 128) valid = 128;
  int tid = threadIdx.x;

  __shared__ __attribute__((aligned(16))) _Float16 As[128 * 32];
  __shared__ __attribute__((aligned(16))) _Float16 Bgs[64 * 32];
  __shared__ __attribute__((aligned(16))) _Float16 Bus[64 * 32];

  // A staging: thread -> (row, chunk pair). 128 rows x 4 chunks(16B) / 256 thr = 2 chunks each
  int arow = tid >> 1;
  int acp = (tid & 1) * 2;
  int crow = (arow < valid) ? arow : (valid - 1);
  const _Float16* aptr = xh + (size_t)btok[base + rt * 128 + crow] * HDIM + acp * 8;
  int awo0 = arow * 32 + ((acp ^ (arow & 3)) * 8);
  int awo1 = arow * 32 + (((acp + 1) ^ (arow & 3)) * 8);

  // B staging: thread -> (row 0..63, quarter 0..3): 8 fp32 -> one 16B fp16 chunk per matrix
  int brow = tid >> 2;
  int q = tid & 3;
  const float* gptr = Wg + (size_t)e * IDIM * HDIM + (size_t)(ct * 64 + brow) * HDIM + q * 8;
  const float* uptr = Wu + (size_t)e * IDIM * HDIM + (size_t)(ct * 64 + brow) * HDIM + q * 8;
  int bwo = brow * 32 + ((q ^ (brow & 3)) * 8);

  int lane = tid & 63, wave = tid >> 6;
  int wm = wave >> 1, wn = wave & 1;
  int lrow = lane & 15, kg = lane >> 4;

  floatx4 accg[4][2] = {};
  floatx4 accu[4][2] = {};

  int aro[4], bro[2];
#pragma unroll
  for (int mi = 0; mi < 4; ++mi) {
    int r = wm * 64 + mi * 16 + lrow;
    aro[mi] = r * 32 + ((kg ^ (r & 3)) * 8);
  }
#pragma unroll
  for (int ni = 0; ni < 2; ++ni) {
    int r = wn * 32 + ni * 16 + lrow;
    bro[ni] = r * 32 + ((kg ^ (r & 3)) * 8);
  }

#pragma unroll 2
  for (int k0 = 0; k0 < HDIM; k0 += 32) {
    uint4 av0 = *(const uint4*)(aptr + k0);
    uint4 av1 = *(const uint4*)(aptr + k0 + 8);
    float4 g0 = *(const float4*)(gptr + k0);
    float4 g1 = *(const float4*)(gptr + k0 + 4);
    float4 u0 = *(const float4*)(uptr + k0);
    float4 u1 = *(const float4*)(uptr + k0 + 4);
    __syncthreads();
    *(uint4*)&As[awo0] = av0;
    *(uint4*)&As[awo1] = av1;
    half8 gh = { (_Float16)g0.x, (_Float16)g0.y, (_Float16)g0.z, (_Float16)g0.w,
                 (_Float16)g1.x, (_Float16)g1.y, (_Float16)g1.z, (_Float16)g1.w };
    half8 uh = { (_Float16)u0.x, (_Float16)u0.y, (_Float16)u0.z, (_Float16)u0.w,
                 (_Float16)u1.x, (_Float16)u1.y, (_Float16)u1.z, (_Float16)u1.w };
    *(half8*)&Bgs[bwo] = gh;
    *(half8*)&Bus[bwo] = uh;
    __syncthreads();
    half8 af[4], bg[2], bu[2];
#pragma unroll
    for (int mi = 0; mi < 4; ++mi) af[mi] = *(half8*)&As[aro[mi]];
#pragma unroll
    for (int ni = 0; ni < 2; ++ni) {
      bg[ni] = *(half8*)&Bgs[bro[ni]];
      bu[ni] = *(half8*)&Bus[bro[ni]];
    }
#pragma unroll
    for (int mi = 0; mi < 4; ++mi) {
#pragma unroll
      for (int ni = 0; ni < 2; ++ni) {
        accg[mi][ni] = __builtin_amdgcn_mfma_f32_16x16x32_f16(af[mi], bg[ni], accg[mi][ni], 0, 0, 0);
        accu[mi][ni] = __builtin_amdgcn_mfma_f32_16x16x32_f16(af[mi], bu[ni], accu[mi][ni], 0, 0, 0);
      }
    }
  }

  size_t hrow_base = (size_t)(base + rt * 128);
#pragma unroll
  for (int mi = 0; mi < 4; ++mi) {
#pragma unroll
    for (int j = 0; j < 4; ++j) {
      int r = wm * 64 + mi * 16 + kg * 4 + j;   // C/D: row=(lane>>4)*4+reg, col=lane&15
      if (r < valid) {
#pragma unroll
        for (int ni = 0; ni < 2; ++ni) {
          float g = accg[mi][ni][j], u = accu[mi][ni][j];
          float hv = g / (1.f + __expf(-g)) * u;   // silu(g)*u
          int c = ct * 64 + wn * 32 + ni * 16 + lrow;
          hb[(hrow_base + r) * IDIM + c] = (_Float16)hv;
        }
      }
    }
  }
}

// ---------------- stage 2: out[tok] += w * (h Wd^T) ----------------
// tile: 128 rows x 128 cols, BK=32, 4 waves (2M x 2N), wave tile 64x64
__global__ __launch_bounds__(256) void stage2_kernel(
    const _Float16* __restrict__ hb, const float* __restrict__ Wd,
    const int* __restrict__ offp, const int* __restrict__ btok, const float* __restrict__ bw,
    float* __restrict__ out) {
  int e = blockIdx.z;
  int base = offp[e];
  int ne = offp[e + 1] - base;
  int rt = blockIdx.y;
  if (rt * 128 >= ne) return;
  int ct = blockIdx.x;                        // 0..15, col base ct*128
  int valid = ne - rt * 128; if (valid > 128) valid = 128;
  int tid = threadIdx.x;

  __shared__ __attribute__((aligned(16))) _Float16 As[128 * 32];
  __shared__ __attribute__((aligned(16))) _Float16 Bs[128 * 32];

  // A staging from hb (fp16, contiguous rows)
  int arow = tid >> 1;
  int acp = (tid & 1) * 2;
  int crow = (arow < valid) ? arow : (valid - 1);
  const _Float16* aptr = hb + (size_t)(base + rt * 128 + crow) * IDIM + acp * 8;
  int awo0 = arow * 32 + ((acp ^ (arow & 3)) * 8);
  int awo1 = arow * 32 + (((acp + 1) ^ (arow & 3)) * 8);

  // B staging from Wd (fp32 -> fp16): thread -> (row 0..127, half 0..1): 16 fp32 -> 2 chunks
  int brow = tid >> 1;
  int hp = tid & 1;
  const float* dptr = Wd + (size_t)e * HDIM * IDIM + (size_t)(ct * 128 + brow) * IDIM + hp * 16;
  int bwo0 = brow * 32 + (((hp * 2) ^ (brow & 3)) * 8);
  int bwo1 = brow * 32 + (((hp * 2 + 1) ^ (brow & 3)) * 8);

  int lane = tid & 63, wave = tid >> 6;
  int wm = wave >> 1, wn = wave & 1;
  int lrow = lane & 15, kg = lane >> 4;

  floatx4 acc[4][4] = {};

  int aro[4], bro[4];
#pragma unroll
  for (int mi = 0; mi < 4; ++mi) {
    int r = wm * 64 + mi * 16 + lrow;
    aro[mi] = r * 32 + ((kg ^ (r & 3)) * 8);
  }
#pragma unroll
  for (int ni = 0; ni < 4; ++ni) {
    int r = wn * 64 + ni * 16 + lrow;
    bro[ni] = r * 32 + ((kg ^ (r & 3)) * 8);
  }

#pragma unroll 2
  for (int k0 = 0; k0 < IDIM; k0 += 32) {
    uint4 av0 = *(const uint4*)(aptr + k0);
    uint4 av1 = *(const uint4*)(aptr + k0 + 8);
    float4 d0 = *(const float4*)(dptr + k0);
    float4 d1 = *(const float4*)(dptr + k0 + 4);
    float4 d2 = *(const float4*)(dptr + k0 + 8);
    float4 d3 = *(const float4*)(dptr + k0 + 12);
    __syncthreads();
    *(uint4*)&As[awo0] = av0;
    *(uint4*)&As[awo1] = av1;
    half8 dh0 = { (_Float16)d0.x, (_Float16)d0.y, (_Float16)d0.z, (_Float16)d0.w,
                  (_Float16)d1.x, (_Float16)d1.y, (_Float16)d1.z, (_Float16)d1.w };
    half8 dh1 = { (_Float16)d2.x, (_Float16)d2.y, (_Float16)d2.z, (_Float16)d2.w,
                  (_Float16)d3.x, (_Float16)d3.y, (_Float16)d3.z, (_Float16)d3.w };
    *(half8*)&Bs[bwo0] = dh0;
    *(half8*)&Bs[bwo1] = dh1;
    __syncthreads();
    half8 af[4], bf[4];
#pragma unroll
    for (int mi = 0; mi < 4; ++mi) af[mi] = *(half8*)&As[aro[mi]];
#pragma unroll
    for (int ni = 0; ni < 4; ++ni) bf[ni] = *(half8*)&Bs[bro[ni]];
#pragma unroll
    for (int mi = 0; mi < 4; ++mi) {
#pragma unroll
      for (int ni = 0; ni < 4; ++ni) {
        acc[mi][ni] = __builtin_amdgcn_mfma_f32_16x16x32_f16(af[mi], bf[ni], acc[mi][ni], 0, 0, 0);
      }
    }
  }

#pragma unroll
  for (int mi = 0; mi < 4; ++mi) {
#pragma unroll
    for (int j = 0; j < 4; ++j) {
      int r = wm * 64 + mi * 16 + kg * 4 + j;
      if (r < valid) {
        int grow = base + rt * 128 + r;
        float w = bw[grow];
        int tok = btok[grow];
#pragma unroll
        for (int ni = 0; ni < 4; ++ni) {
          int c = ct * 128 + wn * 64 + ni * 16 + lrow;
          atomicAdd(&out[(size_t)tok * HDIM + c], acc[mi][ni][j] * w);
        }
      }
    }
  }
}

// ---------------- launch ----------------
extern "C" void kernel_launch(void* const* d_in, const int* in_sizes, int n_in,
                              void* d_out, int out_size, void* d_ws, size_t ws_size,
                              hipStream_t stream) {
  const float* x  = (const float*)d_in[0];
  const float* rw = (const float*)d_in[1];
  const float* Wg = (const float*)d_in[2];
  const float* Wu = (const float*)d_in[3];
  const float* Wd = (const float*)d_in[4];
  float* out = (float*)d_out;

  char* ws = (char*)d_ws;
  _Float16* xh  = (_Float16*)(ws + XH_OFF);
  _Float16* hb  = (_Float16*)(ws + HB_OFF);
  int*      btok = (int*)(ws + BTOK_OFF);
  float*    bwv  = (float*)(ws + BW_OFF);
  int*      tokp = (int*)(ws + TOKP_OFF);
  float2*   tokw = (float2*)(ws + TOKW_OFF);
  int*      meta = (int*)(ws + META_OFF);
  int* cnt = meta;          // [8]
  int* offp = meta + 8;     // [9]
  int* cursor = meta + 20;  // [8]

  hipMemsetAsync(meta, 0, 128, stream);
  hipMemsetAsync(out, 0, (size_t)NTOK * HDIM * sizeof(float), stream);

  cvt_x_kernel<<<2048, 256, 0, stream>>>((const float4*)x, (half4v*)xh, NTOK * HDIM / 4);
  router_kernel<<<NTOK / 4, 256, 0, stream>>>(x, rw, tokp, tokw, cnt);
  scan_kernel<<<1, 64, 0, stream>>>(cnt, offp);
  scatter_kernel<<<NTOK / 256, 256, 0, stream>>>(tokp, tokw, offp, cursor, btok, bwv);
  stage1_kernel<<<dim3(IDIM / 64, 32, NEXP), 256, 0, stream>>>(xh, Wg, Wu, offp, btok, hb);
  stage2_kernel<<<dim3(HDIM / 128, 32, NEXP), 256, 0, stream>>>(hb, Wd, offp, btok, bwv, out);
}